// Round 1
// baseline (345.051 us; speedup 1.0000x reference)
//
#include <hip/hip_runtime.h>
#include <hip/hip_cooperative_groups.h>

namespace cg = cooperative_groups;

// Problem constants (RecurrentGCN / A3TGCN reduction)
constexpr int N_NODES = 20000;
constexpr int P_PER   = 12;
constexpr int N_EDGES = 640000;
constexpr int HID     = 100;

// Single cooperative kernel: 250 blocks (1 per CU at 51.5KB LDS), 256 threads.
constexpr int BIN_W   = 80;                    // nodes per bin
constexpr int NB      = N_NODES / BIN_W;       // 250 bins == 250 blocks (exact)
constexpr int BCAP    = 3136;                  // mean 2560, sigma ~50 -> 11.4 sigma
constexpr int CHUNK   = N_EDGES / NB;          // 2560 edges per block (exact)
constexpr int CUR_STR = 16;                    // cursor padded to one per 64B line
constexpr int Y_STR   = 16;                    // y row stride (floats), 64B rows
constexpr int NPB     = 25;                    // precompute blocks
constexpr int JPB     = HID / NPB;             // 4 j-rows per precompute block

// Workspace layout (4-byte elements). Total ~7.6 MB.
constexpr size_t OFF_PART = 0;                         // 25*4*100 = 10000 floats
constexpr size_t OFF_CUR  = 10000;                     // NB*CUR_STR ints = 4000
constexpr size_t OFF_Y    = 14000;                     // 16B-aligned; N*Y_STR floats
constexpr size_t OFF_SEG  = OFF_Y + (size_t)N_NODES * Y_STR;  // 334000, NB*BCAP pairs

struct EPair { int x, y; };   // POD so it can live inside the LDS union

__global__ __launch_bounds__(256) void fused_all(
    const float* __restrict__ x,   const int* __restrict__ ei,  const float* __restrict__ ew,
    const float* __restrict__ Wz,  const float* __restrict__ bz,
    const float* __restrict__ Wh,  const float* __restrict__ bh,
    const float* __restrict__ Wlz, const float* __restrict__ blz,
    const float* __restrict__ Wlh, const float* __restrict__ blh,
    const float* __restrict__ att, const float* __restrict__ Wout,
    const float* __restrict__ bout,
    float* __restrict__ part, int* __restrict__ cur, float* __restrict__ y,
    EPair* __restrict__ seg, float* __restrict__ out)
{
    // LDS: phase-exclusive regions share one union (ent is the largest member).
    __shared__ union U {
        struct { int hist[NB]; int base[NB]; int run[NB]; } p1;       // partition
        EPair ent[BCAP];                                              // raw bin entries
        struct { float uz[HID], cz[HID], uh[HID], ch[HID], wo[HID], pr[P_PER]; } p3;
    } u;
    __shared__ EPair ent2[BCAP];              // node-sorted bin (persists ph2 -> ph3)
    __shared__ int   hist[BIN_W], excl[BIN_W], off[BIN_W];
    __shared__ float sdinv[BIN_W];

    cg::grid_group grid = cg::this_grid();
    const int t = threadIdx.x;
    const int b = blockIdx.x;

    // ---------------- phase 0: zero this block's bin cursor ----------------
    if (t == 0) cur[(size_t)b * CUR_STR] = 0;
    __threadfence();
    grid.sync();

    // ---------------- phase 1: precompute partials + edge partition --------
    // Rank-1 collapse of (GCN weight @ Wl[:HID]): blocks 0..24 each take 4 j-rows.
    if (b < NPB && t < HID) {
        float suz = 0.f, scz = 0.f, suh = 0.f, sch = 0.f;
#pragma unroll
        for (int jj = 0; jj < JPB; ++jj) {
            int j = b * JPB + jj;
            float wlz = Wlz[j * HID + t];
            float wlh = Wlh[j * HID + t];
            suz += Wz[j] * wlz;  scz += bz[j] * wlz;
            suh += Wh[j] * wlh;  sch += bh[j] * wlh;
        }
        part[(size_t)(4 * b + 0) * HID + t] = suz;
        part[(size_t)(4 * b + 1) * HID + t] = scz;
        part[(size_t)(4 * b + 2) * HID + t] = suh;
        part[(size_t)(4 * b + 3) * HID + t] = sch;
    }
    for (int i = t; i < NB; i += 256) { u.p1.hist[i] = 0; u.p1.run[i] = 0; }
    __syncthreads();
    const int e0 = b * CHUNK;
    const int* __restrict__ dsts = ei + N_EDGES;
    for (int i = t; i < CHUNK; i += 256) {
        int d = dsts[e0 + i];
        atomicAdd(&u.p1.hist[d / BIN_W], 1);
    }
    __syncthreads();
    for (int i = t; i < NB; i += 256) {
        int h = u.p1.hist[i];
        u.p1.base[i] = (h > 0) ? atomicAdd(cur + (size_t)i * CUR_STR, h) : 0;
    }
    __syncthreads();
    for (int i = t; i < CHUNK; i += 256) {
        int s  = ei[e0 + i];
        int d  = dsts[e0 + i];
        float wt = ew[e0 + i];
        int bin = d / BIN_W;
        int dl  = d - bin * BIN_W;
        int pos = u.p1.base[bin] + atomicAdd(&u.p1.run[bin], 1);
        if (pos < BCAP) {
            EPair e; e.x = s | (dl << 16); e.y = __float_as_int(wt);
            seg[(size_t)bin * BCAP + pos] = e;
        }
    }
    __threadfence();
    grid.sync();
    __threadfence();

    // ---------------- phase 2: per-bin counting sort + dinv + y ------------
    if (t < BIN_W) hist[t] = 0;
    __syncthreads();
    const int c = min(cur[(size_t)b * CUR_STR], BCAP);
    const EPair* __restrict__ sg = seg + (size_t)b * BCAP;
    for (int i = t; i < c; i += 256) {
        EPair e = sg[i];
        u.ent[i] = e;
        atomicAdd(&hist[e.x >> 16], 1);
    }
    __syncthreads();
    // exclusive scan over 80 counters: wave0 scans [0,64), wave1 lanes scan [64,80)
    if (t < 64) {
        int v = hist[t], inc = v;
#pragma unroll
        for (int o = 1; o < 64; o <<= 1) {
            int uu = __shfl_up(inc, o, 64);
            if (t >= o) inc += uu;
        }
        excl[t] = inc - v;
    }
    __syncthreads();
    if (t >= 64 && t < BIN_W) {
        int v = hist[t], inc = v;
        int lane = t - 64;
#pragma unroll
        for (int o = 1; o < 16; o <<= 1) {
            int uu = __shfl_up(inc, o, 64);
            if (lane >= o) inc += uu;
        }
        excl[t] = (inc - v) + excl[63] + hist[63];
    }
    __syncthreads();
    if (t < BIN_W) off[t] = excl[t];
    __syncthreads();
    for (int i = t; i < c; i += 256) {
        EPair e = u.ent[i];
        int dl = e.x >> 16;
        int p  = atomicAdd(&off[dl], 1);
        EPair o2; o2.x = e.x & 0xFFFF; o2.y = e.y;
        ent2[p] = o2;
    }
    __syncthreads();
    // weight sums -> dinv (runs are contiguous in ent2, no atomics)
    if (t < BIN_W) {
        int beg = excl[t], end = excl[t] + hist[t];
        float s = 0.f;
        for (int j = beg; j < end; ++j) s += __int_as_float(ent2[j].y);
        sdinv[t] = rsqrtf(1.0f + s);
    }
    __syncthreads();
    const int n0 = b * BIN_W;
    for (int i = t; i < BIN_W * P_PER; i += 256) {
        int nl = i / P_PER, p = i - nl * P_PER;
        y[(size_t)(n0 + nl) * Y_STR + p] = sdinv[nl] * x[(size_t)(n0 + nl) * P_PER + p];
    }
    __threadfence();
    grid.sync();
    __threadfence();

    // ---------------- phase 3: tables + gather + fused epilogue ------------
    if (t < HID) {
        float suz = 0.f, scz = 0.f, suh = 0.f, sch = 0.f;
        for (int bb = 0; bb < NPB; ++bb) {
            suz += part[(size_t)(4 * bb + 0) * HID + t];
            scz += part[(size_t)(4 * bb + 1) * HID + t];
            suh += part[(size_t)(4 * bb + 2) * HID + t];
            sch += part[(size_t)(4 * bb + 3) * HID + t];
        }
        u.p3.uz[t] = suz;
        u.p3.cz[t] = scz + blz[t];
        u.p3.uh[t] = suh;
        u.p3.ch[t] = sch + blh[t];
        u.p3.wo[t] = Wout[t];
    }
    if (t == 0) {
        float m = att[0];
        for (int p = 1; p < P_PER; ++p) m = fmaxf(m, att[p]);
        float e[P_PER]; float ssum = 0.f;
        for (int p = 0; p < P_PER; ++p) { e[p] = __expf(att[p] - m); ssum += e[p]; }
        float inv = 1.0f / ssum;
        for (int p = 0; p < P_PER; ++p) u.p3.pr[p] = e[p] * inv;
    }
    __syncthreads();

    const float bo = bout[0];
    const int l = t & 15;
    const int g = t >> 4;                         // 16 node-groups per pass
    for (int pass = 0; pass < BIN_W / 16; ++pass) {   // 5 passes x 16 nodes = 80
        int nl = pass * 16 + g;
        int n  = n0 + nl;
        int beg = excl[nl], len = hist[nl];
        float acc[P_PER];
#pragma unroll
        for (int p = 0; p < P_PER; ++p) acc[p] = 0.f;
        for (int j = beg + l; j < beg + len; j += 16) {
            EPair e = ent2[j];                    // LDS-resident sorted run
            float wt = __int_as_float(e.y);
            const float4* yr = (const float4*)(y + (size_t)e.x * Y_STR);
            float4 y0 = yr[0], y1 = yr[1], y2 = yr[2];
            acc[0]  += wt * y0.x;  acc[1]  += wt * y0.y;
            acc[2]  += wt * y0.z;  acc[3]  += wt * y0.w;
            acc[4]  += wt * y1.x;  acc[5]  += wt * y1.y;
            acc[6]  += wt * y1.z;  acc[7]  += wt * y1.w;
            acc[8]  += wt * y2.x;  acc[9]  += wt * y2.y;
            acc[10] += wt * y2.z;  acc[11] += wt * y2.w;
        }
#pragma unroll
        for (int o = 8; o >= 1; o >>= 1) {
#pragma unroll
            for (int p = 0; p < P_PER; ++p) acc[p] += __shfl_xor(acc[p], o, 64);
        }
        {
            float dn = sdinv[nl];
            const float4* yr = (const float4*)(y + (size_t)n * Y_STR);
            float4 y0 = yr[0], y1 = yr[1], y2 = yr[2];
            acc[0]  = dn * (acc[0]  + y0.x);  acc[1]  = dn * (acc[1]  + y0.y);
            acc[2]  = dn * (acc[2]  + y0.z);  acc[3]  = dn * (acc[3]  + y0.w);
            acc[4]  = dn * (acc[4]  + y1.x);  acc[5]  = dn * (acc[5]  + y1.y);
            acc[6]  = dn * (acc[6]  + y1.z);  acc[7]  = dn * (acc[7]  + y1.w);
            acc[8]  = dn * (acc[8]  + y2.x);  acc[9]  = dn * (acc[9]  + y2.y);
            acc[10] = dn * (acc[10] + y2.z);  acc[11] = dn * (acc[11] + y2.w);
        }
        float rk = 0.f;
        for (int k = l; k < HID; k += 16) {       // 7 or 6 iterations per lane
            float uzk = u.p3.uz[k], czk = u.p3.cz[k];
            float uhk = u.p3.uh[k], chk = u.p3.ch[k];
            float a2 = 0.f;
#pragma unroll
            for (int p = 0; p < P_PER; ++p) {
                float av = acc[p];
                float vz = fminf(fmaxf(av * uzk + czk, -30.f), 30.f);
                float vh = fminf(fmaxf(av * uhk + chk, -15.f), 15.f);
                float ez  = __expf(vz);
                float e2h = __expf(2.0f * vh);
                float term = (e2h - 1.0f) / ((1.0f + ez) * (e2h + 1.0f));  // sigmoid(-vz)*tanh(vh)
                a2 += u.p3.pr[p] * term;
            }
            rk += fmaxf(a2, 0.0f) * u.p3.wo[k];
        }
#pragma unroll
        for (int o = 8; o >= 1; o >>= 1) rk += __shfl_xor(rk, o, 64);
        if (l == 0) out[n] = rk + bo;
    }
}

extern "C" void kernel_launch(void* const* d_in, const int* in_sizes, int n_in,
                              void* d_out, int out_size, void* d_ws, size_t ws_size,
                              hipStream_t stream) {
    (void)in_sizes; (void)n_in; (void)out_size; (void)ws_size;
    const float* x    = (const float*)d_in[0];
    const int*   ei   = (const int*)d_in[1];
    const float* ew   = (const float*)d_in[2];
    const float* Wz   = (const float*)d_in[3];
    const float* bz   = (const float*)d_in[4];
    // d_in[5], d_in[6]: W_r, b_r — dead (H0 = 0)
    const float* Wh   = (const float*)d_in[7];
    const float* bh   = (const float*)d_in[8];
    const float* Wlz  = (const float*)d_in[9];
    const float* blz  = (const float*)d_in[10];
    // d_in[11], d_in[12]: Wl_r, bl_r — dead
    const float* Wlh  = (const float*)d_in[13];
    const float* blh  = (const float*)d_in[14];
    const float* att  = (const float*)d_in[15];
    const float* Wout = (const float*)d_in[16];
    const float* bout = (const float*)d_in[17];
    float* out = (float*)d_out;

    float* ws   = (float*)d_ws;
    float* part = ws + OFF_PART;
    int*   cur  = (int*)(ws + OFF_CUR);
    float* y    = ws + OFF_Y;
    EPair* seg  = (EPair*)(ws + OFF_SEG);

    void* args[] = { (void*)&x, (void*)&ei, (void*)&ew, (void*)&Wz, (void*)&bz,
                     (void*)&Wh, (void*)&bh, (void*)&Wlz, (void*)&blz,
                     (void*)&Wlh, (void*)&blh, (void*)&att, (void*)&Wout,
                     (void*)&bout, (void*)&part, (void*)&cur, (void*)&y,
                     (void*)&seg, (void*)&out };
    hipLaunchCooperativeKernel((const void*)fused_all, dim3(NB), dim3(256),
                               args, 0, stream);
}

// Round 2
// 183.553 us; speedup vs baseline: 1.8798x; 1.8798x over previous
//
#include <hip/hip_runtime.h>

// Problem constants (RecurrentGCN / A3TGCN reduction)
constexpr int N_NODES = 20000;
constexpr int P_PER   = 12;
constexpr int N_EDGES = 640000;
constexpr int HID     = 100;

constexpr int BIN_W   = 16;                    // nodes per bin (small -> high occupancy in sort+gather)
constexpr int NB      = N_NODES / BIN_W;       // 1250 bins (exact)
constexpr int BCAP    = 768;                   // mean 512, sigma 22.6 -> 11.3 sigma
constexpr int CUR_STR = 16;                    // bin cursor padded to one per 64B line
constexpr int NPB     = 25;                    // blocks doing weight-collapse partials
constexpr int JPB     = HID / NPB;             // 4 j-rows per precompute block
constexpr int NBLK1   = 1280;                  // partition grid (5 blocks/CU)

// Workspace layout (4-byte elements). Total ~7.8 MB.
// [0,400)      : table partial sums uz|cz|uh|ch (atomicAdd targets, zeroed)
// [400,20400)  : wsum[N] (atomicAdd targets, zeroed)
// [20400,40400): cur[NB*CUR_STR] (zeroed)
// [40400,...)  : seg[NB*BCAP] int2
constexpr size_t OFF_TAB  = 0;
constexpr size_t OFF_WSUM = 400;
constexpr size_t OFF_CUR  = 20400;
constexpr size_t OFF_SEG  = 40400;
constexpr size_t ZERO_BYTES = OFF_SEG * 4;     // 161.6 KB, one memset

struct EPair { int x, y; };

// ---------------------------------------------------------------------------
// k1: edge partition into NB bins + wsum atomics + weight-collapse partials.
// Entry: .x = src | (d_local<<16)  [src < 2^16], .y = weight bits.
__global__ __launch_bounds__(256) void partition_kernel(
    const int* __restrict__ ei, const float* __restrict__ ew,
    const float* __restrict__ Wz, const float* __restrict__ bz,
    const float* __restrict__ Wh, const float* __restrict__ bh,
    const float* __restrict__ Wlz, const float* __restrict__ Wlh,
    float* __restrict__ tab, float* __restrict__ wsum,
    int* __restrict__ cur, EPair* __restrict__ seg)
{
    const int t = threadIdx.x;
    const int b = blockIdx.x;

    // rank-1 collapse of (GCN weight @ Wl[:HID]) -> 4 table rows, 25 blocks x 4 rows
    if (b < NPB && t < HID) {
        float suz = 0.f, scz = 0.f, suh = 0.f, sch = 0.f;
#pragma unroll
        for (int jj = 0; jj < JPB; ++jj) {
            int j = b * JPB + jj;
            float wlz = Wlz[j * HID + t];
            float wlh = Wlh[j * HID + t];
            suz += Wz[j] * wlz;  scz += bz[j] * wlz;
            suh += Wh[j] * wlh;  sch += bh[j] * wlh;
        }
        atomicAdd(&tab[t],           suz);
        atomicAdd(&tab[HID + t],     scz);
        atomicAdd(&tab[2 * HID + t], suh);
        atomicAdd(&tab[3 * HID + t], sch);
    }

    const int* __restrict__ dsts = ei + N_EDGES;
    const int stride = NBLK1 * 256;
    for (int i = b * 256 + t; i < N_EDGES; i += stride) {
        int s   = ei[i];
        int d   = dsts[i];
        float w = ew[i];
        atomicAdd(&wsum[d], w);
        int bin = d >> 4;
        int dl  = d & 15;
        int pos = atomicAdd(cur + (size_t)bin * CUR_STR, 1);
        if (pos < BCAP) {
            EPair e; e.x = s | (dl << 16); e.y = __float_as_int(w);
            seg[(size_t)bin * BCAP + pos] = e;
        }
    }
}

// ---------------------------------------------------------------------------
// k2: per-bin LDS counting sort + gather + fused epilogue. 1250 blocks, the
// sorted bin never leaves LDS; dinv recomputed per edge from global wsum.
__global__ __launch_bounds__(256) void sort_gather_kernel(
    const EPair* __restrict__ seg, const int* __restrict__ cur,
    const float* __restrict__ wsum, const float* __restrict__ x,
    const float* __restrict__ tab,
    const float* __restrict__ blz, const float* __restrict__ blh,
    const float* __restrict__ att, const float* __restrict__ Wout,
    const float* __restrict__ bout, float* __restrict__ out)
{
    __shared__ EPair ent[BCAP];               // staged raw entries (6KB)
    __shared__ EPair ent2[BCAP];              // node-sorted entries (6KB)
    __shared__ int   hist[BIN_W], excl[BIN_W], off[BIN_W];
    __shared__ float s_uz[HID], s_cz[HID], s_uh[HID], s_ch[HID], s_wo[HID];
    __shared__ float s_pr[P_PER];

    const int t = threadIdx.x;
    const int b = blockIdx.x;

    if (t < HID) {
        s_uz[t] = tab[t];
        s_cz[t] = tab[HID + t] + blz[t];
        s_uh[t] = tab[2 * HID + t];
        s_ch[t] = tab[3 * HID + t] + blh[t];
        s_wo[t] = Wout[t];
    }
    if (t == 0) {
        float m = att[0];
        for (int p = 1; p < P_PER; ++p) m = fmaxf(m, att[p]);
        float e[P_PER]; float ssum = 0.f;
        for (int p = 0; p < P_PER; ++p) { e[p] = __expf(att[p] - m); ssum += e[p]; }
        float inv = 1.0f / ssum;
        for (int p = 0; p < P_PER; ++p) s_pr[p] = e[p] * inv;
    }
    if (t < BIN_W) hist[t] = 0;
    __syncthreads();

    const int c = min(cur[(size_t)b * CUR_STR], BCAP);
    const EPair* __restrict__ sg = seg + (size_t)b * BCAP;
    for (int i = t; i < c; i += 256) {
        EPair e = sg[i];
        ent[i] = e;
        atomicAdd(&hist[e.x >> 16], 1);
    }
    __syncthreads();
    // exclusive scan over 16 counters (one wave)
    if (t < 64) {
        int v = (t < BIN_W) ? hist[t] : 0;
        int inc = v;
#pragma unroll
        for (int o = 1; o < BIN_W; o <<= 1) {
            int uu = __shfl_up(inc, o, 64);
            if (t >= o) inc += uu;
        }
        if (t < BIN_W) { excl[t] = inc - v; off[t] = inc - v; }
    }
    __syncthreads();
    for (int i = t; i < c; i += 256) {
        EPair e = ent[i];
        int dl = e.x >> 16;
        int p  = atomicAdd(&off[dl], 1);
        EPair o2; o2.x = e.x & 0xFFFF; o2.y = e.y;
        ent2[p] = o2;
    }
    __syncthreads();

    // gather: 16 lanes per node, exactly one pass (16 nodes x 16 lanes = 256)
    const int nl = t >> 4, l = t & 15;
    const int n  = b * BIN_W + nl;
    const float dn = rsqrtf(1.0f + wsum[n]);
    float acc[P_PER];
#pragma unroll
    for (int p = 0; p < P_PER; ++p) acc[p] = 0.f;
    const int beg = excl[nl], len = hist[nl];
    for (int j = beg + l; j < beg + len; j += 16) {
        EPair e = ent2[j];
        int s  = e.x;
        float cw = __int_as_float(e.y) * rsqrtf(1.0f + wsum[s]);
        const float4* xr = (const float4*)(x + (size_t)s * P_PER);   // 48B rows, 16B aligned
        float4 x0 = xr[0], x1 = xr[1], x2 = xr[2];
        acc[0]  += cw * x0.x;  acc[1]  += cw * x0.y;
        acc[2]  += cw * x0.z;  acc[3]  += cw * x0.w;
        acc[4]  += cw * x1.x;  acc[5]  += cw * x1.y;
        acc[6]  += cw * x1.z;  acc[7]  += cw * x1.w;
        acc[8]  += cw * x2.x;  acc[9]  += cw * x2.y;
        acc[10] += cw * x2.z;  acc[11] += cw * x2.w;
    }
    // self-loop term (weight 1): dinv[n]*x[n], added by lane 0 before the reduce
    if (l == 0) {
        const float4* xr = (const float4*)(x + (size_t)n * P_PER);
        float4 x0 = xr[0], x1 = xr[1], x2 = xr[2];
        acc[0]  += dn * x0.x;  acc[1]  += dn * x0.y;
        acc[2]  += dn * x0.z;  acc[3]  += dn * x0.w;
        acc[4]  += dn * x1.x;  acc[5]  += dn * x1.y;
        acc[6]  += dn * x1.z;  acc[7]  += dn * x1.w;
        acc[8]  += dn * x2.x;  acc[9]  += dn * x2.y;
        acc[10] += dn * x2.z;  acc[11] += dn * x2.w;
    }
#pragma unroll
    for (int o = 8; o >= 1; o >>= 1) {
#pragma unroll
        for (int p = 0; p < P_PER; ++p) acc[p] += __shfl_xor(acc[p], o, 64);
    }
#pragma unroll
    for (int p = 0; p < P_PER; ++p) acc[p] *= dn;   // a[p] = dinv[n]*(sum + self)

    float rk = 0.f;
    for (int k = l; k < HID; k += 16) {             // 7 or 6 iterations per lane
        float uzk = s_uz[k], czk = s_cz[k], uhk = s_uh[k], chk = s_ch[k];
        float a2 = 0.f;
#pragma unroll
        for (int p = 0; p < P_PER; ++p) {
            float av = acc[p];
            float vz = fminf(fmaxf(av * uzk + czk, -30.f), 30.f);
            float vh = fminf(fmaxf(av * uhk + chk, -15.f), 15.f);
            float ez  = __expf(vz);
            float e2h = __expf(2.0f * vh);
            float term = (e2h - 1.0f) / ((1.0f + ez) * (e2h + 1.0f));  // sigmoid(-vz)*tanh(vh)
            a2 += s_pr[p] * term;
        }
        rk += fmaxf(a2, 0.0f) * s_wo[k];
    }
#pragma unroll
    for (int o = 8; o >= 1; o >>= 1) rk += __shfl_xor(rk, o, 64);
    if (l == 0) out[n] = rk + bout[0];
}

extern "C" void kernel_launch(void* const* d_in, const int* in_sizes, int n_in,
                              void* d_out, int out_size, void* d_ws, size_t ws_size,
                              hipStream_t stream) {
    (void)in_sizes; (void)n_in; (void)out_size; (void)ws_size;
    const float* x    = (const float*)d_in[0];
    const int*   ei   = (const int*)d_in[1];
    const float* ew   = (const float*)d_in[2];
    const float* Wz   = (const float*)d_in[3];
    const float* bz   = (const float*)d_in[4];
    // d_in[5], d_in[6]: W_r, b_r — dead (H0 = 0)
    const float* Wh   = (const float*)d_in[7];
    const float* bh   = (const float*)d_in[8];
    const float* Wlz  = (const float*)d_in[9];
    const float* blz  = (const float*)d_in[10];
    // d_in[11], d_in[12]: Wl_r, bl_r — dead
    const float* Wlh  = (const float*)d_in[13];
    const float* blh  = (const float*)d_in[14];
    const float* att  = (const float*)d_in[15];
    const float* Wout = (const float*)d_in[16];
    const float* bout = (const float*)d_in[17];
    float* out = (float*)d_out;

    float* ws   = (float*)d_ws;
    float* tab  = ws + OFF_TAB;
    float* wsum = ws + OFF_WSUM;
    int*   cur  = (int*)(ws + OFF_CUR);
    EPair* seg  = (EPair*)(ws + OFF_SEG);

    hipMemsetAsync(ws, 0, ZERO_BYTES, stream);
    hipLaunchKernelGGL(partition_kernel, dim3(NBLK1), dim3(256), 0, stream,
                       ei, ew, Wz, bz, Wh, bh, Wlz, Wlh, tab, wsum, cur, seg);
    hipLaunchKernelGGL(sort_gather_kernel, dim3(NB), dim3(256), 0, stream,
                       seg, cur, wsum, x, tab, blz, blh, att, Wout, bout, out);
}

// Round 3
// 179.411 us; speedup vs baseline: 1.9232x; 1.0231x over previous
//
#include <hip/hip_runtime.h>

// Problem constants (RecurrentGCN / A3TGCN reduction)
constexpr int N_NODES = 20000;
constexpr int P_PER   = 12;
constexpr int N_EDGES = 640000;
constexpr int HID     = 100;

constexpr int BIN_W   = 32;                    // nodes per bin
constexpr int NB      = N_NODES / BIN_W;       // 625 bins (exact)
constexpr int BCAP    = 1408;                  // mean 1024, sigma 32 -> 12 sigma
constexpr int CUR_STR = 16;                    // bin cursor padded to one per 64B line
constexpr int NPB     = 25;                    // blocks doing weight-collapse partials
constexpr int JPB     = HID / NPB;             // 4 j-rows per precompute block
constexpr int NBLK1   = 160;                   // partition grid
constexpr int CHUNK   = N_EDGES / NBLK1;       // 4000 edges per block (exact)

// Workspace layout (4-byte elements). Total ~7.2 MB.
// [0,400)      : table partial sums uz|cz|uh|ch (atomicAdd targets, zeroed)
// [400,20400)  : wsum[N] (atomicAdd targets, zeroed)
// [20400,30400): cur[NB*CUR_STR] (zeroed)
// [30400,...)  : seg[NB*BCAP] int2
constexpr size_t OFF_TAB  = 0;
constexpr size_t OFF_WSUM = 400;
constexpr size_t OFF_CUR  = 20400;
constexpr size_t OFF_SEG  = 30400;
constexpr size_t ZERO_BYTES = OFF_SEG * 4;     // 121.6 KB, one memset

struct EPair { int x, y; };

// ---------------------------------------------------------------------------
// k1: edge partition. Per-block LDS histogram -> ONE cursor atomic per
// (block,bin) -> scatter into the block's contiguous run (line-friendly:
// runs of ~6.4 entries assembled in this XCD's L2, ~1 writeback per line).
// Entry: .x = src | (d_local<<16)  [src < 2^16], .y = weight bits.
// Also: wsum[d] atomics and the rank-1 weight-collapse partials (blocks 0-24).
__global__ __launch_bounds__(256) void partition_kernel(
    const int* __restrict__ ei, const float* __restrict__ ew,
    const float* __restrict__ Wz, const float* __restrict__ bz,
    const float* __restrict__ Wh, const float* __restrict__ bh,
    const float* __restrict__ Wlz, const float* __restrict__ Wlh,
    float* __restrict__ tab, float* __restrict__ wsum,
    int* __restrict__ cur, EPair* __restrict__ seg)
{
    __shared__ int hist[NB];
    __shared__ int base[NB];
    __shared__ int run[NB];
    const int t = threadIdx.x;
    const int b = blockIdx.x;

    // rank-1 collapse of (GCN weight @ Wl[:HID]) -> 4 table rows, 25 blocks x 4 rows
    if (b < NPB && t < HID) {
        float suz = 0.f, scz = 0.f, suh = 0.f, sch = 0.f;
#pragma unroll
        for (int jj = 0; jj < JPB; ++jj) {
            int j = b * JPB + jj;
            float wlz = Wlz[j * HID + t];
            float wlh = Wlh[j * HID + t];
            suz += Wz[j] * wlz;  scz += bz[j] * wlz;
            suh += Wh[j] * wlh;  sch += bh[j] * wlh;
        }
        atomicAdd(&tab[t],           suz);
        atomicAdd(&tab[HID + t],     scz);
        atomicAdd(&tab[2 * HID + t], suh);
        atomicAdd(&tab[3 * HID + t], sch);
    }

    for (int i = t; i < NB; i += 256) { hist[i] = 0; run[i] = 0; }
    __syncthreads();

    const int e0 = b * CHUNK;
    const int* __restrict__ dsts = ei + N_EDGES;
    for (int i = t; i < CHUNK; i += 256) {
        int d   = dsts[e0 + i];
        float w = ew[e0 + i];
        atomicAdd(&wsum[d], w);
        atomicAdd(&hist[d >> 5], 1);
    }
    __syncthreads();
    // one global reservation atomic per nonzero (block,bin)
    for (int i = t; i < NB; i += 256) {
        int h = hist[i];
        base[i] = (h > 0) ? atomicAdd(cur + (size_t)i * CUR_STR, h) : 0;
    }
    __syncthreads();
    // scatter into this block's contiguous runs
    for (int i = t; i < CHUNK; i += 256) {
        int s   = ei[e0 + i];
        int d   = dsts[e0 + i];
        float w = ew[e0 + i];
        int bin = d >> 5;
        int dl  = d & 31;
        int pos = base[bin] + atomicAdd(&run[bin], 1);
        if (pos < BCAP) {
            EPair e; e.x = s | (dl << 16); e.y = __float_as_int(w);
            seg[(size_t)bin * BCAP + pos] = e;
        }
    }
}

// ---------------------------------------------------------------------------
// k2: per-bin LDS counting sort + gather + fused epilogue. 625 blocks; the
// sorted bin never leaves LDS; dinv recomputed per edge from global wsum.
__global__ __launch_bounds__(256) void sort_gather_kernel(
    const EPair* __restrict__ seg, const int* __restrict__ cur,
    const float* __restrict__ wsum, const float* __restrict__ x,
    const float* __restrict__ tab,
    const float* __restrict__ blz, const float* __restrict__ blh,
    const float* __restrict__ att, const float* __restrict__ Wout,
    const float* __restrict__ bout, float* __restrict__ out)
{
    __shared__ EPair ent[BCAP];               // staged raw entries (11.3KB)
    __shared__ EPair ent2[BCAP];              // node-sorted entries (11.3KB)
    __shared__ int   hist[BIN_W], excl[BIN_W], off[BIN_W];
    __shared__ float s_uz[HID], s_cz[HID], s_uh[HID], s_ch[HID], s_wo[HID];
    __shared__ float s_pr[P_PER];

    const int t = threadIdx.x;
    const int b = blockIdx.x;

    if (t < HID) {
        s_uz[t] = tab[t];
        s_cz[t] = tab[HID + t] + blz[t];
        s_uh[t] = tab[2 * HID + t];
        s_ch[t] = tab[3 * HID + t] + blh[t];
        s_wo[t] = Wout[t];
    }
    if (t == 0) {
        float m = att[0];
        for (int p = 1; p < P_PER; ++p) m = fmaxf(m, att[p]);
        float e[P_PER]; float ssum = 0.f;
        for (int p = 0; p < P_PER; ++p) { e[p] = __expf(att[p] - m); ssum += e[p]; }
        float inv = 1.0f / ssum;
        for (int p = 0; p < P_PER; ++p) s_pr[p] = e[p] * inv;
    }
    if (t < BIN_W) hist[t] = 0;
    __syncthreads();

    const int c = min(cur[(size_t)b * CUR_STR], BCAP);
    const EPair* __restrict__ sg = seg + (size_t)b * BCAP;
    for (int i = t; i < c; i += 256) {
        EPair e = sg[i];
        ent[i] = e;
        atomicAdd(&hist[e.x >> 16], 1);
    }
    __syncthreads();
    // exclusive scan over 32 counters (one wave)
    if (t < 64) {
        int v = (t < BIN_W) ? hist[t] : 0;
        int inc = v;
#pragma unroll
        for (int o = 1; o < BIN_W; o <<= 1) {
            int uu = __shfl_up(inc, o, 64);
            if (t >= o) inc += uu;
        }
        if (t < BIN_W) { excl[t] = inc - v; off[t] = inc - v; }
    }
    __syncthreads();
    for (int i = t; i < c; i += 256) {
        EPair e = ent[i];
        int dl = e.x >> 16;
        int p  = atomicAdd(&off[dl], 1);
        EPair o2; o2.x = e.x & 0xFFFF; o2.y = e.y;
        ent2[p] = o2;
    }
    __syncthreads();

    // gather: 8 lanes per node, one pass (32 nodes x 8 lanes = 256)
    const int nl = t >> 3, l = t & 7;
    const int n  = b * BIN_W + nl;
    const float dn = rsqrtf(1.0f + wsum[n]);
    float acc[P_PER];
#pragma unroll
    for (int p = 0; p < P_PER; ++p) acc[p] = 0.f;
    const int beg = excl[nl], len = hist[nl];
    for (int j = beg + l; j < beg + len; j += 8) {
        EPair e = ent2[j];
        int s  = e.x;
        float cw = __int_as_float(e.y) * rsqrtf(1.0f + wsum[s]);
        const float4* xr = (const float4*)(x + (size_t)s * P_PER);   // 48B rows, 16B aligned
        float4 x0 = xr[0], x1 = xr[1], x2 = xr[2];
        acc[0]  += cw * x0.x;  acc[1]  += cw * x0.y;
        acc[2]  += cw * x0.z;  acc[3]  += cw * x0.w;
        acc[4]  += cw * x1.x;  acc[5]  += cw * x1.y;
        acc[6]  += cw * x1.z;  acc[7]  += cw * x1.w;
        acc[8]  += cw * x2.x;  acc[9]  += cw * x2.y;
        acc[10] += cw * x2.z;  acc[11] += cw * x2.w;
    }
    // self-loop term (weight 1): dinv[n]*x[n], added by lane 0 before the reduce
    if (l == 0) {
        const float4* xr = (const float4*)(x + (size_t)n * P_PER);
        float4 x0 = xr[0], x1 = xr[1], x2 = xr[2];
        acc[0]  += dn * x0.x;  acc[1]  += dn * x0.y;
        acc[2]  += dn * x0.z;  acc[3]  += dn * x0.w;
        acc[4]  += dn * x1.x;  acc[5]  += dn * x1.y;
        acc[6]  += dn * x1.z;  acc[7]  += dn * x1.w;
        acc[8]  += dn * x2.x;  acc[9]  += dn * x2.y;
        acc[10] += dn * x2.z;  acc[11] += dn * x2.w;
    }
#pragma unroll
    for (int o = 4; o >= 1; o >>= 1) {
#pragma unroll
        for (int p = 0; p < P_PER; ++p) acc[p] += __shfl_xor(acc[p], o, 64);
    }
#pragma unroll
    for (int p = 0; p < P_PER; ++p) acc[p] *= dn;   // a[p] = dinv[n]*(sum + self)

    float rk = 0.f;
    for (int k = l; k < HID; k += 8) {              // 13 or 12 iterations per lane
        float uzk = s_uz[k], czk = s_cz[k], uhk = s_uh[k], chk = s_ch[k];
        float a2 = 0.f;
#pragma unroll
        for (int p = 0; p < P_PER; ++p) {
            float av = acc[p];
            float vz = fminf(fmaxf(av * uzk + czk, -30.f), 30.f);
            float vh = fminf(fmaxf(av * uhk + chk, -15.f), 15.f);
            float ez  = __expf(vz);
            float e2h = __expf(2.0f * vh);
            float term = (e2h - 1.0f) / ((1.0f + ez) * (e2h + 1.0f));  // sigmoid(-vz)*tanh(vh)
            a2 += s_pr[p] * term;
        }
        rk += fmaxf(a2, 0.0f) * s_wo[k];
    }
#pragma unroll
    for (int o = 4; o >= 1; o >>= 1) rk += __shfl_xor(rk, o, 64);
    if (l == 0) out[n] = rk + bout[0];
}

extern "C" void kernel_launch(void* const* d_in, const int* in_sizes, int n_in,
                              void* d_out, int out_size, void* d_ws, size_t ws_size,
                              hipStream_t stream) {
    (void)in_sizes; (void)n_in; (void)out_size; (void)ws_size;
    const float* x    = (const float*)d_in[0];
    const int*   ei   = (const int*)d_in[1];
    const float* ew   = (const float*)d_in[2];
    const float* Wz   = (const float*)d_in[3];
    const float* bz   = (const float*)d_in[4];
    // d_in[5], d_in[6]: W_r, b_r — dead (H0 = 0)
    const float* Wh   = (const float*)d_in[7];
    const float* bh   = (const float*)d_in[8];
    const float* Wlz  = (const float*)d_in[9];
    const float* blz  = (const float*)d_in[10];
    // d_in[11], d_in[12]: Wl_r, bl_r — dead
    const float* Wlh  = (const float*)d_in[13];
    const float* blh  = (const float*)d_in[14];
    const float* att  = (const float*)d_in[15];
    const float* Wout = (const float*)d_in[16];
    const float* bout = (const float*)d_in[17];
    float* out = (float*)d_out;

    float* ws   = (float*)d_ws;
    float* tab  = ws + OFF_TAB;
    float* wsum = ws + OFF_WSUM;
    int*   cur  = (int*)(ws + OFF_CUR);
    EPair* seg  = (EPair*)(ws + OFF_SEG);

    hipMemsetAsync(ws, 0, ZERO_BYTES, stream);
    hipLaunchKernelGGL(partition_kernel, dim3(NBLK1), dim3(256), 0, stream,
                       ei, ew, Wz, bz, Wh, bh, Wlz, Wlh, tab, wsum, cur, seg);
    hipLaunchKernelGGL(sort_gather_kernel, dim3(NB), dim3(256), 0, stream,
                       seg, cur, wsum, x, tab, blz, blh, att, Wout, bout, out);
}